// Round 5
// baseline (119.661 us; speedup 1.0000x reference)
//
#include <hip/hip_runtime.h>
#include <hip/hip_bf16.h>

// Problem constants (from reference): B=64, N=1024, D=8, S=16
#define BB 64
#define NN 1024
#define DD 8
#define SS 16
#define DS 128           // D*S

typedef __attribute__((ext_vector_type(8))) short short8;
typedef __attribute__((ext_vector_type(4))) float floatx4;

typedef __attribute__((address_space(1))) const unsigned int glds_src;
typedef __attribute__((address_space(3))) unsigned int glds_dst;

static __device__ __forceinline__ unsigned short f2bf(float f) {
    unsigned int u = __float_as_uint(f);
    unsigned int r = (u + 0x7FFFu + ((u >> 16) & 1u)) >> 16;   // RNE
    return (unsigned short)r;
}

// ---------------- Kernel 1: merged prepass (UNCHANGED, verified) ----------------
__global__ void prepass(const float* __restrict__ x, unsigned short* __restrict__ xT,
                        const float* __restrict__ M, unsigned short* __restrict__ Mb) {
    __shared__ float tile[64 * 68];          // 64x64 fp32 tile, stride 68 (16B-aligned rows)
    const int t = threadIdx.x;

    if (blockIdx.x < 1024) {                 // ---- convert_M part ----
        int i = (blockIdx.x * 256 + t) * 4;
        float4 v = *(const float4*)(M + i);
        unsigned int p0 = (unsigned int)f2bf(v.x) | ((unsigned int)f2bf(v.y) << 16);
        unsigned int p1 = (unsigned int)f2bf(v.z) | ((unsigned int)f2bf(v.w) << 16);
        *(uint2*)(Mb + i) = make_uint2(p0, p1);
        return;
    }

    // ---- transpose part ----
    const int bid = blockIdx.x - 1024;
    const int i0 = (bid & 15) * 64;
    const int c0 = ((bid >> 4) & 1) * 64;
    const int b  = bid >> 5;
    const float* xb = x + (size_t)b * (NN * DS);

#pragma unroll
    for (int jj = 0; jj < 4; ++jj) {
        int il = (t >> 4) + jj * 16;         // 0..63
        int cl = (t & 15) * 4;               // 0..60
        float4 v = *(const float4*)(xb + (size_t)(i0 + il) * DS + c0 + cl);
        *(float4*)(tile + il * 68 + cl) = v;
    }
    __syncthreads();
    int cr  = t >> 2;                        // 0..63 : local ds row
    int iq  = (t & 3) * 16;                  // i sub-offset
    int rot = (t & 3) * 2;                   // j-rotation: breaks the 4-way bank conflict
    unsigned int p[8];
#pragma unroll
    for (int j = 0; j < 8; ++j) {
        int jp = (j + rot) & 7;
        unsigned short lo = f2bf(tile[(iq + 2 * jp + 0) * 68 + cr]);
        unsigned short hi = f2bf(tile[(iq + 2 * jp + 1) * 68 + cr]);
        p[jp] = (unsigned int)lo | ((unsigned int)hi << 16);
    }
    unsigned short* dst = xT + (size_t)b * (NN * DS) + (size_t)(c0 + cr) * NN + i0 + iq;
    *(uint4*)(dst + 0) = make_uint4(p[0], p[1], p[2], p[3]);
    *(uint4*)(dst + 8) = make_uint4(p[4], p[5], p[6], p[7]);
}

// ---------------- Kernel 2: fused GEMM, T3-minimum 2-phase (stage-early, double-buffer) ----------------
// R0 plateau analysis: single-buffered loop exposes the full glds flight (L2 ~200-400cy
// x 16 lines/instr) 8 times: {barrier; STAGE(kt); drain-barrier; COMPUTE(kt)} has zero
// stage/compute overlap. T3's verified minimum recipe (m248v2, +10% same-probe): issue
// STAGE(kt+1) into the OTHER buffer BEFORE COMPUTE(kt), then one __syncthreads per tile
// (its vmcnt(0) is the stage-wait, hidden behind ~32 MFMAs of compute).
// Constraint kept (violated by failed R1/R2): BK=64 -> LDS 2x(16+16)+1 = 65 KB ->
// 2 blocks/CU, 8 waves/CU, same 4-wave 128x128 geometry + verified epilogue as R0.
// Swizzle for 128B rows (8 granules of 16B): store slot s of row r holds granule
// s^(r&7) (glds source pre-swizzle); read slot ((ks*4+kq)^(lm&7)). Rows are exactly
// one 32-bank cycle (128B) so banks depend only on slot: per frag-read, slot-group
// = (ks*4+kq)^(lm&7) covers each of 8 groups exactly 8x -> same uniform pattern as
// R0's verified XOR-16 (conflict-free).
// WAR safety: STAGE(kt+1) writes buf^1, last read by COMPUTE(kt-1) whose ds_reads
// completed before their MFMAs (compiler lgkmcnt), all waves past the end-of-(kt-1)
// __syncthreads. RAW: COMPUTE(kt) reads buf staged at iter kt-1, drained by that
// iter's __syncthreads (vmcnt(0)).
__global__ __launch_bounds__(256, 2) void gemm_fused(
    const unsigned short* __restrict__ Mb,   // [N][N] bf16, row o, col i (k-contiguous)
    const unsigned short* __restrict__ xT,   // [B][DS][N] bf16, row ds, col i (k-contiguous)
    const float* __restrict__ w_syn,         // [N][D][S]
    const float* __restrict__ b_dend,        // [N][D]
    const float* __restrict__ w_dend,        // [N][D]
    const float* __restrict__ b_soma,        // [N]
    float* __restrict__ out)                 // [B][N]
{
    __shared__ __align__(16) unsigned short As[2 * 128 * 64];  // 32 KB (o rows, BK=64, dbuf)
    __shared__ __align__(16) unsigned short Bs[2 * 128 * 64];  // 32 KB (ds rows)
    __shared__ float ex[128 * 2];                              //  1 KB soma exchange

    const int t      = threadIdx.x;
    const int b      = blockIdx.x;            // b fastest -> XCD = b%8: xT[b] pinned per XCD
    const int o_base = blockIdx.y * 128;

    const char* AgB = (const char*)(Mb + (size_t)o_base * NN);
    const char* BgB = (const char*)(xT + (size_t)b * (NN * DS));

    const int lane = t & 63;
    const int w    = t >> 6;
    const int wr   = (w >> 1) * 64;           // wave row offset (o)
    const int wc   = (w & 1) * 64;            // wave col offset (ds)
    const int lm   = lane & 15;
    const int kq   = lane >> 4;               // 0..3

    // staging: one glds = 64 lanes x 16B = 8 rows x 128B. LDS slot (lane&7) of row
    // base+(lane>>3) holds global granule (lane&7)^(row&7).
    const int r8 = lane >> 3, l8 = lane & 7;
    const int sg = (l8 ^ r8) * 16;
    int off[4], ldsb[4];
#pragma unroll
    for (int j = 0; j < 4; ++j) {
        const int row = w * 32 + j * 8 + r8;   // tile row (same distribution for A & B)
        off[j]  = row * (NN * 2) + sg;
        ldsb[j] = (w * 4 + j) * 1024;          // wave-uniform LDS byte base; +lane*16 implicit
    }

#define STAGE(TT, BUF) do { const int kb_ = (TT) * 128;                                               \
    _Pragma("unroll")                                                                                 \
    for (int j_ = 0; j_ < 4; ++j_) {                                                                  \
        __builtin_amdgcn_global_load_lds((glds_src*)(AgB + off[j_] + kb_),                            \
            (glds_dst*)((char*)As + (BUF) * 16384 + ldsb[j_]), 16, 0, 0);                             \
        __builtin_amdgcn_global_load_lds((glds_src*)(BgB + off[j_] + kb_),                            \
            (glds_dst*)((char*)Bs + (BUF) * 16384 + ldsb[j_]), 16, 0, 0);                             \
    }                                                                                                 \
} while (0)

#define COMPUTE(BUF) do {                                                                             \
    _Pragma("unroll")                                                                                 \
    for (int ks_ = 0; ks_ < 2; ++ks_) {                                                               \
        short8 af_[4], bf_[4];                                                                        \
        const int g_ = (((ks_ * 4 + kq) ^ (lm & 7)) * 8);                                             \
        _Pragma("unroll")                                                                             \
        for (int r_ = 0; r_ < 4; ++r_)                                                                \
            af_[r_] = *(const short8*)(As + (BUF) * 8192 + (wr + r_ * 16 + lm) * 64 + g_);            \
        _Pragma("unroll")                                                                             \
        for (int c_ = 0; c_ < 4; ++c_)                                                                \
            bf_[c_] = *(const short8*)(Bs + (BUF) * 8192 + (wc + c_ * 16 + lm) * 64 + g_);            \
        _Pragma("unroll")                                                                             \
        for (int r_ = 0; r_ < 4; ++r_)                                                                \
            _Pragma("unroll")                                                                         \
            for (int c_ = 0; c_ < 4; ++c_)                                                            \
                acc[r_][c_] = __builtin_amdgcn_mfma_f32_16x16x32_bf16(af_[r_], bf_[c_], acc[r_][c_], 0, 0, 0); \
    }                                                                                                 \
} while (0)

    floatx4 acc[4][4] = {};

    // prologue: stage tile 0, wait (only exposed stage of the whole loop)
    STAGE(0, 0);
    __syncthreads();                           // drains vmcnt(0): tile 0 staged

#pragma unroll
    for (int kt = 0; kt < 15; ++kt) {
        STAGE(kt + 1, (kt + 1) & 1);           // issue EARLY: flies under COMPUTE(kt)
        COMPUTE(kt & 1);
        __syncthreads();                       // vmcnt(0): tile kt+1 staged; all reads of buf kt done
    }
    COMPUTE(1);                                // kt = 15, no further stage

#undef STAGE
#undef COMPUTE

    // ---- register epilogue (byte-identical to verified R0) ----
    // C/D layout: for acc[r][c][reg]: o = o_base+wr+r*16+kq*4+reg, ds = wc+c*16+lm
    // => dendrite d = (w&1)*4 + c, synapse s = lm. Butterfly over lm (within quad-16).
    float keep[4];
#pragma unroll
    for (int r = 0; r < 4; ++r) {
#pragma unroll
        for (int rg = 0; rg < 4; ++rg) {
            const int o = o_base + wr + r * 16 + kq * 4 + rg;
#pragma unroll
            for (int c = 0; c < 4; ++c) {
                const int d = (w & 1) * 4 + c;
                float p = acc[r][c][rg] * w_syn[o * DS + d * SS + lm];
                p += __shfl_xor(p, 1);
                p += __shfl_xor(p, 2);
                p += __shfl_xor(p, 4);
                p += __shfl_xor(p, 8);         // all 16 lanes of the quad now hold sum_s
                if (lm == r * 4 + rg) keep[c] = p;
            }
        }
    }
    // each lane finalizes one o: lane lm encodes (r=lm>>2, reg=lm&3)
    {
        const int o_loc = wr + (lm >> 2) * 16 + kq * 4 + (lm & 3);
        const int o     = o_base + o_loc;
        float part = 0.f;
#pragma unroll
        for (int c = 0; c < 4; ++c) {
            const int d = (w & 1) * 4 + c;
            float pre = keep[c] + b_dend[o * DD + d];
            part += tanhf(pre) * w_dend[o * DD + d];
        }
        ex[o_loc * 2 + (w & 1)] = part;        // waves (0,1) cover o 0..63, (2,3) o 64..127
    }
    __syncthreads();
    if (t < 128) {
        float soma = ex[t * 2] + ex[t * 2 + 1] + b_soma[o_base + t];
        out[(size_t)b * NN + o_base + t] = 1.f / (1.f + __expf(-soma));
    }
}

extern "C" void kernel_launch(void* const* d_in, const int* in_sizes, int n_in,
                              void* d_out, int out_size, void* d_ws, size_t ws_size,
                              hipStream_t stream) {
    const float* x      = (const float*)d_in[0];   // [B,N,D,S]
    const float* M      = (const float*)d_in[1];   // [N,N]
    const float* w_syn  = (const float*)d_in[2];   // [N,D,S]
    const float* b_dend = (const float*)d_in[3];   // [N,D]
    const float* w_dend = (const float*)d_in[4];   // [N,D]
    const float* b_soma = (const float*)d_in[5];   // [N]
    float* out = (float*)d_out;

    unsigned short* xT = (unsigned short*)d_ws;                 // [B][DS][N] bf16 : 16 MiB
    unsigned short* Mb = xT + (size_t)BB * NN * DS;             // [N][N]   bf16 :  2 MiB

    prepass   <<<dim3(1024 + 2048), 256, 0, stream>>>(x, xT, M, Mb);
    gemm_fused<<<dim3(BB, NN / 128), 256, 0, stream>>>(Mb, xT, w_syn, b_dend, w_dend, b_soma, out);
}

// Round 6
// 108.633 us; speedup vs baseline: 1.1015x; 1.1015x over previous
//
#include <hip/hip_runtime.h>
#include <hip/hip_bf16.h>

// Problem constants (from reference): B=64, N=1024, D=8, S=16
#define BB 64
#define NN 1024
#define DD 8
#define SS 16
#define DS 128           // D*S

typedef __attribute__((ext_vector_type(8))) short short8;
typedef __attribute__((ext_vector_type(4))) float floatx4;

typedef __attribute__((address_space(1))) const unsigned int glds_src;
typedef __attribute__((address_space(3))) unsigned int glds_dst;

static __device__ __forceinline__ unsigned short f2bf(float f) {
    unsigned int u = __float_as_uint(f);
    unsigned int r = (u + 0x7FFFu + ((u >> 16) & 1u)) >> 16;   // RNE
    return (unsigned short)r;
}

// ---------------- Kernel 1: merged prepass ----------------
// blocks [0,1024): convert matriz_conexao (values exactly 0.0/1.0) fp32 -> bf16
// blocks [1024,3072): x[b][i][ds] fp32 -> xT[b][ds][i] bf16 (k-contiguous GEMM B operand)
__global__ void prepass(const float* __restrict__ x, unsigned short* __restrict__ xT,
                        const float* __restrict__ M, unsigned short* __restrict__ Mb) {
    __shared__ float tile[64 * 68];          // 64x64 fp32 tile, stride 68 (16B-aligned rows)
    const int t = threadIdx.x;

    if (blockIdx.x < 1024) {                 // ---- convert_M part ----
        int i = (blockIdx.x * 256 + t) * 4;
        float4 v = *(const float4*)(M + i);
        unsigned int p0 = (unsigned int)f2bf(v.x) | ((unsigned int)f2bf(v.y) << 16);
        unsigned int p1 = (unsigned int)f2bf(v.z) | ((unsigned int)f2bf(v.w) << 16);
        *(uint2*)(Mb + i) = make_uint2(p0, p1);
        return;
    }

    // ---- transpose part ----
    const int bid = blockIdx.x - 1024;
    const int i0 = (bid & 15) * 64;
    const int c0 = ((bid >> 4) & 1) * 64;
    const int b  = bid >> 5;
    const float* xb = x + (size_t)b * (NN * DS);

#pragma unroll
    for (int jj = 0; jj < 4; ++jj) {
        int il = (t >> 4) + jj * 16;         // 0..63
        int cl = (t & 15) * 4;               // 0..60
        float4 v = *(const float4*)(xb + (size_t)(i0 + il) * DS + c0 + cl);
        *(float4*)(tile + il * 68 + cl) = v;
    }
    __syncthreads();
    int cr  = t >> 2;                        // 0..63 : local ds row
    int iq  = (t & 3) * 16;                  // i sub-offset
    int rot = (t & 3) * 2;                   // j-rotation: breaks the 4-way bank conflict
    unsigned int p[8];
#pragma unroll
    for (int j = 0; j < 8; ++j) {
        int jp = (j + rot) & 7;
        unsigned short lo = f2bf(tile[(iq + 2 * jp + 0) * 68 + cr]);
        unsigned short hi = f2bf(tile[(iq + 2 * jp + 1) * 68 + cr]);
        p[jp] = (unsigned int)lo | ((unsigned int)hi << 16);
    }
    unsigned short* dst = xT + (size_t)b * (NN * DS) + (size_t)(c0 + cr) * NN + i0 + iq;
    *(uint4*)(dst + 0) = make_uint4(p[0], p[1], p[2], p[3]);
    *(uint4*)(dst + 8) = make_uint4(p[4], p[5], p[6], p[7]);
}

// ---------------- Kernel 2: fused GEMM (xm = M @ x_b) + dendrite tanh + soma sigmoid ----------------
// VERIFIED BEST (108.3-108.6 us across three sessions). grid = (B, N/128); block 256 (4 waves).
// Tile 128 o x 128 ds, BK=128 (8 iters), single-buffered two-barrier glds loop.
// Structural plateau ledger (this problem, K=1024 = 8 K-steps):
//   R1 8-phase 256-tile port      111.4  (1 block/CU, lockstep barriers)
//   R2 counted-vmcnt triple-buf   115.3  (same occupancy loss)
//   R3 LDS-free direct fragments  160.7  (MfmaUtil 7.9%: 16-line scatter per wave-load)
//   R5 T3-minimum 2-phase BK=64   119.7  (stage flight > compute cover; 2x barriers)
// Three comparable resources (L2 stage ~7.4us, LDS read ~10us, MFMA ~7us) meet at the
// 2-barrier chain; every deeper schedule pays occupancy/barriers/coalescing that 8
// K-steps cannot amortize (m201's regime is 64+). Per learn_hip m131-m141 this
// structure is a fixed point at HIP source level.
__global__ __launch_bounds__(256, 2) void gemm_fused(
    const unsigned short* __restrict__ Mb,   // [N][N] bf16, row o, col i (k-contiguous)
    const unsigned short* __restrict__ xT,   // [B][DS][N] bf16, row ds, col i (k-contiguous)
    const float* __restrict__ w_syn,         // [N][D][S]
    const float* __restrict__ b_dend,        // [N][D]
    const float* __restrict__ w_dend,        // [N][D]
    const float* __restrict__ b_soma,        // [N]
    float* __restrict__ out)                 // [B][N]
{
    __shared__ __align__(16) unsigned short As[128 * 128];  // 32 KB (o rows, BK=128)
    __shared__ __align__(16) unsigned short Bs[128 * 128];  // 32 KB (ds rows, BK=128)
    __shared__ float ex[128 * 2];                           // 1 KB soma exchange

    const int t      = threadIdx.x;
    const int b      = blockIdx.x;            // b fastest -> XCD = b%8: xT[b] pinned per XCD
    const int o_base = blockIdx.y * 128;

    const char* AgB = (const char*)(Mb + (size_t)o_base * NN);
    const char* BgB = (const char*)(xT + (size_t)b * (NN * DS));

    const int lane = t & 63;
    const int w    = t >> 6;
    const int wr   = (w >> 1) * 64;           // wave row offset (o)
    const int wc   = (w & 1) * 64;            // wave col offset (ds)
    const int lm   = lane & 15;
    const int kq   = lane >> 4;               // 0..3

    // staging: glds j (0..7) of wave w covers rows (w*8+j)*4 + (lane>>4), 16 granules/row.
    // Source granule for LDS slot (lane&15) is (lane&15)^(row&15)  (XOR-16 swizzle).
    int off[8], ldsb[8];
#pragma unroll
    for (int j = 0; j < 8; ++j) {
        const int row = (w * 8 + j) * 4 + (lane >> 4);
        const int sg  = (lane & 15) ^ (row & 15);
        off[j]  = row * (NN * 2) + sg * 16;
        ldsb[j] = (w * 8 + j) * 1024;          // wave-uniform base; +lane*16 is implicit
    }

    floatx4 acc[4][4] = {};

    for (int kt = 0; kt < 8; ++kt) {
        const int kb = kt * 256;               // byte offset along k within a row (BK=128)
        __syncthreads();                       // previous tile's frag reads done
#pragma unroll
        for (int j = 0; j < 8; ++j) {
            __builtin_amdgcn_global_load_lds((glds_src*)(AgB + off[j] + kb),
                                             (glds_dst*)((char*)As + ldsb[j]), 16, 0, 0);
            __builtin_amdgcn_global_load_lds((glds_src*)(BgB + off[j] + kb),
                                             (glds_dst*)((char*)Bs + ldsb[j]), 16, 0, 0);
        }
        __syncthreads();                       // drains vmcnt(0): tile staged
#pragma unroll
        for (int ks = 0; ks < 4; ++ks) {
            short8 af[4], bf[4];
            const int g = (((ks * 4 + kq) ^ lm) * 8);   // swizzled ushort offset in 128-row
#pragma unroll
            for (int r = 0; r < 4; ++r)
                af[r] = *(const short8*)(As + (wr + r * 16 + lm) * 128 + g);
#pragma unroll
            for (int c = 0; c < 4; ++c)
                bf[c] = *(const short8*)(Bs + (wc + c * 16 + lm) * 128 + g);
#pragma unroll
            for (int r = 0; r < 4; ++r)
#pragma unroll
                for (int c = 0; c < 4; ++c)
                    acc[r][c] = __builtin_amdgcn_mfma_f32_16x16x32_bf16(af[r], bf[c], acc[r][c], 0, 0, 0);
        }
    }

    // ---- register epilogue (verified) ----
    // C/D layout: for acc[r][c][reg]: o = o_base+wr+r*16+kq*4+reg, ds = wc+c*16+lm
    // => dendrite d = (w&1)*4 + c, synapse s = lm. Butterfly over lm (within quad-16).
    float keep[4];
#pragma unroll
    for (int r = 0; r < 4; ++r) {
#pragma unroll
        for (int rg = 0; rg < 4; ++rg) {
            const int o = o_base + wr + r * 16 + kq * 4 + rg;
#pragma unroll
            for (int c = 0; c < 4; ++c) {
                const int d = (w & 1) * 4 + c;
                float p = acc[r][c][rg] * w_syn[o * DS + d * SS + lm];
                p += __shfl_xor(p, 1);
                p += __shfl_xor(p, 2);
                p += __shfl_xor(p, 4);
                p += __shfl_xor(p, 8);         // all 16 lanes of the quad now hold sum_s
                if (lm == r * 4 + rg) keep[c] = p;
            }
        }
    }
    // each lane finalizes one o: lane lm encodes (r=lm>>2, reg=lm&3)
    {
        const int o_loc = wr + (lm >> 2) * 16 + kq * 4 + (lm & 3);
        const int o     = o_base + o_loc;
        float part = 0.f;
#pragma unroll
        for (int c = 0; c < 4; ++c) {
            const int d = (w & 1) * 4 + c;
            float pre = keep[c] + b_dend[o * DD + d];
            part += tanhf(pre) * w_dend[o * DD + d];
        }
        ex[o_loc * 2 + (w & 1)] = part;        // waves (0,1) cover o 0..63, (2,3) o 64..127
    }
    __syncthreads();
    if (t < 128) {
        float soma = ex[t * 2] + ex[t * 2 + 1] + b_soma[o_base + t];
        out[(size_t)b * NN + o_base + t] = 1.f / (1.f + __expf(-soma));
    }
}

extern "C" void kernel_launch(void* const* d_in, const int* in_sizes, int n_in,
                              void* d_out, int out_size, void* d_ws, size_t ws_size,
                              hipStream_t stream) {
    const float* x      = (const float*)d_in[0];   // [B,N,D,S]
    const float* M      = (const float*)d_in[1];   // [N,N]
    const float* w_syn  = (const float*)d_in[2];   // [N,D,S]
    const float* b_dend = (const float*)d_in[3];   // [N,D]
    const float* w_dend = (const float*)d_in[4];   // [N,D]
    const float* b_soma = (const float*)d_in[5];   // [N]
    float* out = (float*)d_out;

    unsigned short* xT = (unsigned short*)d_ws;                 // [B][DS][N] bf16 : 16 MiB
    unsigned short* Mb = xT + (size_t)BB * NN * DS;             // [N][N]   bf16 :  2 MiB

    prepass   <<<dim3(1024 + 2048), 256, 0, stream>>>(x, xT, M, Mb);
    gemm_fused<<<dim3(BB, NN / 128), 256, 0, stream>>>(Mb, xT, w_syn, b_dend, w_dend, b_soma, out);
}